// Round 12
// baseline (379.735 us; speedup 1.0000x reference)
//
#include <hip/hip_runtime.h>

#define N_F     64
#define N_REL   32
#define BLOCK   256
#define SCAN_TILE 2048

typedef __attribute__((ext_vector_type(8))) short bf16x8;   // 8 bf16 = 4 VGPRs
typedef __attribute__((ext_vector_type(4))) float f32x4;

__device__ __forceinline__ unsigned short f2bf(float f) {
    unsigned u = __float_as_uint(f);
    u += 0x7FFF + ((u >> 16) & 1);          // RNE
    return (unsigned short)(u >> 16);
}

// ---------------------------------------------------------------------------
// K-pre: region-branched fusion of cast | relw | hist.
// Hist blocks persist their per-rel histogram to bh (no hot cnt1 atomics —
// cnt1 is recomputed as bh row-sums in k_scan_mid).
// ---------------------------------------------------------------------------
__global__ void __launch_bounds__(BLOCK) k_pre(const float* __restrict__ nf,
                                               const int* __restrict__ rel,
                                               const int* __restrict__ rcv,
                                               const float* __restrict__ basis,
                                               const float* __restrict__ coeff,
                                               unsigned short* __restrict__ xbf,
                                               unsigned short* __restrict__ Wsh,
                                               int* __restrict__ S,    // [0,N): cnt2, [N,..): bh
                                               int E, int total4, int N, int nbh,
                                               int nbCast, int nbRelw) {
    const int bid = blockIdx.x;
    if (bid < nbCast) {
        int i = bid * BLOCK + threadIdx.x;
        if (i < total4) {
            float4 v = ((const float4*)nf)[i];
            ushort4 o;
            o.x = f2bf(v.x); o.y = f2bf(v.y); o.z = f2bf(v.z); o.w = f2bf(v.w);
            ((ushort4*)xbf)[i] = o;
        }
    } else if (bid < nbCast + nbRelw) {
        int idx = (bid - nbCast) * BLOCK + threadIdx.x;
        if (idx < N_REL * N_F * N_F) {
            int r  = idx >> 12;
            int io = idx & 4095;          // k*64 + n
            int k  = io >> 6;
            int n  = io & 63;
            float acc = 0.f;
#pragma unroll
            for (int b = 0; b < 30; ++b)
                acc += coeff[r * 30 + b] * basis[b * (N_F * N_F) + io];
            int ks = k >> 5, kk = k & 31;
            int nt = n >> 4, nl = n & 15;
            int lane = ((kk >> 3) << 4) | nl;
            int j    = kk & 7;
            Wsh[((((r * 2 + ks) * 4 + nt) * 64 + lane) << 3) + j] = f2bf(acc);
        }
    } else {
        __shared__ int h[N_REL];
        if (threadIdx.x < N_REL) h[threadIdx.x] = 0;
        __syncthreads();
        const int bidh = bid - nbCast - nbRelw;
        int e = bidh * BLOCK + threadIdx.x;
        if (e < E) {
            atomicAdd(&h[rel[e]], 1);
            atomicAdd(&S[rcv[e]], 1);          // cnt2 (scattered, benign)
        }
        __syncthreads();
        if (threadIdx.x < N_REL)
            S[N + threadIdx.x * nbh + bidh] = h[threadIdx.x];   // bh (plain store)
    }
}

// ---------------------------------------------------------------------------
// Scan stage 1 over the combined array S = [cnt2 | bh]
// ---------------------------------------------------------------------------
__global__ void k_scan_sums(const int* __restrict__ cur, int* __restrict__ part,
                            int nbins) {
    __shared__ int red[BLOCK];
    int base = blockIdx.x * SCAN_TILE;
    int s = 0;
    for (int i = threadIdx.x; i < SCAN_TILE; i += BLOCK) {
        int idx = base + i;
        s += (idx < nbins) ? cur[idx] : 0;
    }
    red[threadIdx.x] = s;
    __syncthreads();
    for (int off = BLOCK / 2; off > 0; off >>= 1) {
        if (threadIdx.x < off) red[threadIdx.x] += red[threadIdx.x + off];
        __syncthreads();
    }
    if (threadIdx.x == 0) part[blockIdx.x] = red[0];
}

// ---------------------------------------------------------------------------
// Single-block middle: (a) cnt1 = bh row-sums (8 thr/rel, contiguous chunks)
// (b) scan of tile sums (c) rel-bin bases padded+unpadded (d) pad-slot init
// incl. tail. No global atomics anywhere.
// ---------------------------------------------------------------------------
__global__ void k_scan_mid(const int* __restrict__ S, int* __restrict__ base1,
                           int* __restrict__ ub1, int* __restrict__ part,
                           int* __restrict__ esrc, int* __restrict__ perm,
                           int npart, int Ppad, int N, int nbh) {
    __shared__ int buf[BLOCK];
    __shared__ int sred[BLOCK];
    __shared__ int scnt[N_REL];
    __shared__ int sbase[N_REL + 1];
    __shared__ int stotal;
    const int tid = threadIdx.x;

    // (a) cnt1 row sums
    {
        const int r     = tid >> 3;
        const int sub   = tid & 7;
        const int chunk = (nbh + 7) >> 3;
        int st = sub * chunk;
        int en = min(st + chunk, nbh);
        int s = 0;
        const int* row = S + N + r * nbh;
        for (int i = st; i < en; ++i) s += row[i];
        sred[tid] = s;
    }
    __syncthreads();
    if ((tid & 7) < 4) sred[tid] += sred[tid + 4];
    __syncthreads();
    if ((tid & 7) < 2) sred[tid] += sred[tid + 2];
    __syncthreads();
    if ((tid & 7) == 0) sred[tid] += sred[tid + 1];
    __syncthreads();
    if (tid < N_REL) scnt[tid] = sred[tid * 8];
    __syncthreads();

    // (b) part scan
    int v = (tid < npart) ? part[tid] : 0;
    buf[tid] = v;
    __syncthreads();
    for (int off = 1; off < BLOCK; off <<= 1) {
        int t = (tid >= off) ? buf[tid - off] : 0;
        __syncthreads();
        buf[tid] += t;
        __syncthreads();
    }
    if (tid < npart) part[tid] = buf[tid] - v;

    // (c) bases
    if (tid == 0) {
        int acc = 0, uacc = 0;
        for (int r = 0; r < N_REL; ++r) {
            base1[r] = acc;
            sbase[r] = acc;
            ub1[r]   = uacc;
            acc  += (scnt[r] + 15) & ~15;
            uacc += scnt[r];
        }
        base1[N_REL] = Ppad;
        sbase[N_REL] = Ppad;
        ub1[N_REL]   = uacc;
        stotal = acc;                  // actual padded total (<= Ppad)
    }
    __syncthreads();

    // (d) intra-bin pad slots
    for (int i = tid; i < N_REL * 16; i += BLOCK) {
        int r = i >> 4, o = i & 15;
        int c  = scnt[r];
        int p0 = sbase[r] + c;
        int p1 = sbase[r] + ((c + 15) & ~15);
        int p  = p0 + o;
        if (p < p1) { perm[p] = -1; esrc[p] = 0; }
    }
    // tail [actual_total, Ppad)
    for (int p = stotal + tid; p < Ppad; p += BLOCK) {
        perm[p] = -1; esrc[p] = 0;
    }
}

// ---------------------------------------------------------------------------
// Scan stage 3 over S (+ fused tile->relation table)
// ---------------------------------------------------------------------------
__global__ void k_scan_apply_tile(int* __restrict__ cur, const int* __restrict__ part,
                                  const int* __restrict__ base1,
                                  unsigned char* __restrict__ trel,
                                  int nbins, int npart, int T) {
    if ((int)blockIdx.x >= npart) {
        int t = (blockIdx.x - npart) * BLOCK + threadIdx.x;
        if (t < T) {
            int p = t << 4;
            int r = 0;
#pragma unroll
            for (int i = 1; i < N_REL; ++i) r += (p >= base1[i]);
            trel[t] = (unsigned char)r;
        }
        return;
    }
    __shared__ int buf[BLOCK];
    int base_t = blockIdx.x * SCAN_TILE + threadIdx.x * 8;
    int loc[8];
    int s = 0;
#pragma unroll
    for (int j = 0; j < 8; ++j) {
        int idx = base_t + j;
        int v = (idx < nbins) ? cur[idx] : 0;
        loc[j] = s;
        s += v;
    }
    buf[threadIdx.x] = s;
    __syncthreads();
    for (int off = 1; off < BLOCK; off <<= 1) {
        int t = (threadIdx.x >= off) ? buf[threadIdx.x - off] : 0;
        __syncthreads();
        buf[threadIdx.x] += t;
        __syncthreads();
    }
    int excl = buf[threadIdx.x] - s + part[blockIdx.x];
#pragma unroll
    for (int j = 0; j < 8; ++j) {
        int idx = base_t + j;
        if (idx < nbins) cur[idx] = loc[j] + excl;
    }
}

// ---------------------------------------------------------------------------
// Scatter: pos1 via per-block scanned base + LDS rank (NO global atomics);
// pos2 via mild scattered cur2 atomic. One barrier.
// S[0,N) = cur2 bases -> end pointers; S[N + r*nbh + b] = scanned bh (+E).
// ---------------------------------------------------------------------------
__global__ void __launch_bounds__(BLOCK) k_scatter1(const int* __restrict__ snd,
                                                    const int* __restrict__ rcv,
                                                    const int* __restrict__ rel,
                                                    int* S,
                                                    const int* __restrict__ base1,
                                                    const int* __restrict__ ub1,
                                                    int* __restrict__ esrc,
                                                    int* __restrict__ perm,
                                                    int E, int N, int nbh) {
    __shared__ int h[N_REL], bhb[N_REL];
    const int b = blockIdx.x;
    if (threadIdx.x < N_REL) {
        int g = S[N + threadIdx.x * nbh + b];              // includes +E offset
        bhb[threadIdx.x] = base1[threadIdx.x] + (g - E - ub1[threadIdx.x]);
        h[threadIdx.x] = 0;
    }
    __syncthreads();
    int e = b * BLOCK + threadIdx.x;
    if (e < E) {
        int r = rel[e];
        int rank = atomicAdd(&h[r], 1);
        int pos1 = bhb[r] + rank;
        int pos2 = atomicAdd(&S[rcv[e]], 1);
        esrc[pos1] = snd[e];
        perm[pos1] = pos2;
    }
}

// ---------------------------------------------------------------------------
// Phase A: per-tile GEMM -> bf16 edge rows at receiver-sorted positions.
// 1-deep prefetch of next tile's esrc/perm. No barriers/atomics.
// ---------------------------------------------------------------------------
__global__ void __launch_bounds__(BLOCK) k_gemm(const unsigned short* __restrict__ xbf,
                                                const int* __restrict__ esrc,
                                                const int* __restrict__ perm,
                                                const unsigned char* __restrict__ trel,
                                                const unsigned short* __restrict__ Wsh,
                                                unsigned short* __restrict__ eoutb,
                                                int T, int tpw, int dumprow) {
    __shared__ float ts[4][16 * 68];        // per-wave 16x64 transpose, stride 68
    const int tid  = threadIdx.x;
    const int lane = tid & 63;
    const int wave = tid >> 6;
    float* tb = ts[wave];

    const int gw = blockIdx.x * 4 + wave;
    const int t0 = gw * tpw;
    const int t1 = min(t0 + tpw, T);
    if (t0 >= T) return;

    const int row = lane & 15;
    const int kg  = lane >> 4;
    const int rr  = lane >> 2;      // store-phase row
    const int ch  = lane & 3;       // store-phase 16-col chunk

    int curR = -1;
    bf16x8 wf[2][4];

    int s_cur  = esrc[(t0 << 4) + row];
    int pm_cur = perm[(t0 << 4) + row];

    for (int t = t0; t < t1; ++t) {
        int s_nxt = 0, pm_nxt = -1;
        if (t + 1 < t1) {
            s_nxt  = esrc[((t + 1) << 4) + row];
            pm_nxt = perm[((t + 1) << 4) + row];
        }

        const int r = trel[t];
        if (r != curR) {
            curR = r;
#pragma unroll
            for (int ks = 0; ks < 2; ++ks)
#pragma unroll
                for (int nt = 0; nt < 4; ++nt)
                    wf[ks][nt] = *(const bf16x8*)(Wsh + ((((r * 2 + ks) * 4 + nt) * 64 + lane) << 3));
        }

        const size_t xb = ((size_t)s_cur << 6) + (kg << 3);
        bf16x8 a0 = *(const bf16x8*)(xbf + xb);
        bf16x8 a1 = *(const bf16x8*)(xbf + xb + 32);

        f32x4 acc[4];
#pragma unroll
        for (int nt = 0; nt < 4; ++nt) {
            acc[nt] = (f32x4){0.f, 0.f, 0.f, 0.f};
            acc[nt] = __builtin_amdgcn_mfma_f32_16x16x32_bf16(a0, wf[0][nt], acc[nt], 0, 0, 0);
            acc[nt] = __builtin_amdgcn_mfma_f32_16x16x32_bf16(a1, wf[1][nt], acc[nt], 0, 0, 0);
        }

        // C-layout (col=lane&15, row=kg*4+reg) -> LDS row-major
#pragma unroll
        for (int nt = 0; nt < 4; ++nt)
#pragma unroll
            for (int reg = 0; reg < 4; ++reg)
                tb[(kg * 4 + reg) * 68 + nt * 16 + (lane & 15)] = acc[nt][reg];

        asm volatile("s_waitcnt lgkmcnt(0)" ::: "memory");   // wave-local RAW

        int pmr = __shfl(pm_cur, rr);         // dest row of store-phase row
        pmr = (pmr < 0) ? dumprow : pmr;      // pad rows -> dump

        const float* src = tb + rr * 68 + ch * 16;
        unsigned pk[8];
#pragma unroll
        for (int q = 0; q < 4; ++q) {
            float4 v = *(const float4*)(src + q * 4);
            pk[2 * q]     = (unsigned)f2bf(v.x) | ((unsigned)f2bf(v.y) << 16);
            pk[2 * q + 1] = (unsigned)f2bf(v.z) | ((unsigned)f2bf(v.w) << 16);
        }
        unsigned short* dst = eoutb + (size_t)pmr * 64 + ch * 16;
        uint4 v0; v0.x = pk[0]; v0.y = pk[1]; v0.z = pk[2]; v0.w = pk[3];
        uint4 v1; v1.x = pk[4]; v1.y = pk[5]; v1.z = pk[6]; v1.w = pk[7];
        *(uint4*)dst       = v0;
        *(uint4*)(dst + 8) = v1;

        s_cur = s_nxt; pm_cur = pm_nxt;
    }
}

// ---------------------------------------------------------------------------
// Phase B: wave per node. 2-rows-per-load (g = lane>>5, c = lane&31; one
// dword = 2 bf16, 256 B/wave-load). Reduction = 1 shfl_xor + 2 shfls +
// select. Span boundaries prefetched. bf16 self-loop. No atomics/LDS.
// ---------------------------------------------------------------------------
__global__ void __launch_bounds__(BLOCK) k_recv(const unsigned short* __restrict__ xbf,
                                                const unsigned short* __restrict__ eoutb,
                                                const int* __restrict__ cur2,
                                                const float* __restrict__ selfw,
                                                const float* __restrict__ bias,
                                                float* __restrict__ out,
                                                int N, int rpw) {
    const int tid  = threadIdx.x;
    const int lane = tid & 63;
    const int wave = tid >> 6;
    const int gw   = blockIdx.x * 4 + wave;
    const int n0   = gw * rpw;
    const int n1   = min(n0 + rpw, N);
    if (n0 >= N) return;

    const int g = lane >> 5;        // row parity
    const int c = lane & 31;        // feat-pair index (feats 2c, 2c+1)

    float swcol[N_F];
#pragma unroll
    for (int i = 0; i < N_F; ++i) swcol[i] = selfw[i * N_F + lane];
    const float bv = bias[lane];

    // prefetch span boundaries: lane l holds cur2[n0-1+l]
    int bidx = n0 - 1 + lane;
    int bnd  = 0;
    if (bidx >= 0 && bidx < N && lane <= (n1 - n0)) bnd = cur2[bidx];

    for (int n = n0; n < n1; ++n) {
        const int li = n - n0;
        const int st = __shfl(bnd, li);
        const int en = __shfl(bnd, li + 1);

        float a0 = 0.f, a1 = 0.f;
        int j = st;
        for (; j + 4 <= en; j += 4) {
            unsigned u0 = *(const unsigned*)(eoutb + ((size_t)(j + g)     << 6) + (c << 1));
            unsigned u1 = *(const unsigned*)(eoutb + ((size_t)(j + 2 + g) << 6) + (c << 1));
            a0 += __uint_as_float(u0 << 16) + __uint_as_float(u1 << 16);
            a1 += __uint_as_float(u0 & 0xFFFF0000u) + __uint_as_float(u1 & 0xFFFF0000u);
        }
        for (; j < en; j += 2) {
            int row = j + g;        // overread row <= en < Ppad: safe, masked
            unsigned u = *(const unsigned*)(eoutb + ((size_t)row << 6) + (c << 1));
            if (row < en) {
                a0 += __uint_as_float(u << 16);
                a1 += __uint_as_float(u & 0xFFFF0000u);
            }
        }
        a0 += __shfl_xor(a0, 32);
        a1 += __shfl_xor(a1, 32);
        float v0 = __shfl(a0, lane >> 1);
        float v1 = __shfl(a1, lane >> 1);
        float agg = (lane & 1) ? v1 : v0;

        // self-loop from bf16 x (broadcast uint4 = 8 feats)
        const uint4* xr = (const uint4*)(xbf + ((size_t)n << 6));
        float s0 = 0.f, s1 = 0.f, s2 = 0.f, s3 = 0.f;
#pragma unroll
        for (int q = 0; q < 8; ++q) {
            uint4 u = xr[q];
            float x0 = __uint_as_float(u.x << 16);
            float x1 = __uint_as_float(u.x & 0xFFFF0000u);
            float x2 = __uint_as_float(u.y << 16);
            float x3 = __uint_as_float(u.y & 0xFFFF0000u);
            float x4 = __uint_as_float(u.z << 16);
            float x5 = __uint_as_float(u.z & 0xFFFF0000u);
            float x6 = __uint_as_float(u.w << 16);
            float x7 = __uint_as_float(u.w & 0xFFFF0000u);
            s0 = __builtin_fmaf(x0, swcol[8 * q + 0], s0);
            s1 = __builtin_fmaf(x1, swcol[8 * q + 1], s1);
            s2 = __builtin_fmaf(x2, swcol[8 * q + 2], s2);
            s3 = __builtin_fmaf(x3, swcol[8 * q + 3], s3);
            s0 = __builtin_fmaf(x4, swcol[8 * q + 4], s0);
            s1 = __builtin_fmaf(x5, swcol[8 * q + 5], s1);
            s2 = __builtin_fmaf(x6, swcol[8 * q + 6], s2);
            s3 = __builtin_fmaf(x7, swcol[8 * q + 7], s3);
        }

        float dg  = (float)(en - st);
        float inv = 1.f / (dg < 1.f ? 1.f : dg);
        out[(size_t)n * N_F + lane] = agg * inv + (s0 + s1) + (s2 + s3) + bv;
    }
}

// ---------------------------------------------------------------------------
extern "C" void kernel_launch(void* const* d_in, const int* in_sizes, int n_in,
                              void* d_out, int out_size, void* d_ws, size_t ws_size,
                              hipStream_t stream) {
    const float* nf    = (const float*)d_in[0];
    const int*   snd   = (const int*)  d_in[1];
    const int*   rcv   = (const int*)  d_in[2];
    const int*   rel   = (const int*)  d_in[3];
    const float* basis = (const float*)d_in[4];
    const float* coeff = (const float*)d_in[5];
    const float* selfw = (const float*)d_in[6];
    const float* bias  = (const float*)d_in[7];
    float*       out   = (float*)d_out;

    const int N = in_sizes[0] / N_F;                  // 100000
    const int E = in_sizes[1];                        // 1000000
    const int Ppad = (E + N_REL * 15 + 15) & ~15;     // padded rel-sorted length
    const int T    = Ppad >> 4;                       // total 16-edge tiles
    const int total4 = N * N_F / 4;

    const int NB_CAST = (total4 + BLOCK - 1) / BLOCK;
    const int NB_RELW = (N_REL * N_F * N_F + BLOCK - 1) / BLOCK;
    const int NB_HIST = (E + BLOCK - 1) / BLOCK;      // == nbh
    const int nbh     = NB_HIST;

    const int SCAN_N = N + N_REL * nbh;               // combined scan length
    const int NPART  = (SCAN_N + SCAN_TILE - 1) / SCAN_TILE;   // <= 256

    // ws layout
    unsigned short* eoutb = (unsigned short*)d_ws;                    // Ppad*64 bf16
    unsigned short* Wsh   = eoutb + (size_t)Ppad * N_F;               // 131072
    unsigned short* xbf   = Wsh + (size_t)N_REL * N_F * N_F;          // N*64
    int* base1 = (int*)(xbf + (size_t)N * N_F);                       // 64
    int* ub1   = base1 + 64;                                          // 64
    int* part  = ub1 + 64;                                            // 256
    int* S     = part + 256;                                          // SCAN_N (memset)
    int* esrc  = S + SCAN_N;                                          // Ppad
    int* perm  = esrc + Ppad;                                         // Ppad
    unsigned char* trel = (unsigned char*)(perm + Ppad);              // T

    hipMemsetAsync(S, 0, (size_t)SCAN_N * sizeof(int), stream);

    k_pre<<<NB_CAST + NB_RELW + NB_HIST, BLOCK, 0, stream>>>(
        nf, rel, rcv, basis, coeff, xbf, Wsh, S, E, total4, N, nbh, NB_CAST, NB_RELW);

    k_scan_sums<<<NPART, BLOCK, 0, stream>>>(S, part, SCAN_N);
    k_scan_mid <<<1,     BLOCK, 0, stream>>>(S, base1, ub1, part, esrc, perm,
                                             NPART, Ppad, N, nbh);

    const int NB_TREL = (T + BLOCK - 1) / BLOCK;
    k_scan_apply_tile<<<NPART + NB_TREL, BLOCK, 0, stream>>>(S, part, base1, trel,
                                                             SCAN_N, NPART, T);

    k_scatter1<<<nbh, BLOCK, 0, stream>>>(snd, rcv, rel, S, base1, ub1, esrc, perm,
                                          E, N, nbh);

    const int GEMM_BLOCKS = 2048;                      // 8192 waves
    const int tpw = (T + GEMM_BLOCKS * 4 - 1) / (GEMM_BLOCKS * 4);
    k_gemm<<<GEMM_BLOCKS, BLOCK, 0, stream>>>(xbf, esrc, perm, trel, Wsh, eoutb, T, tpw, E);

    const int RECV_BLOCKS = 4096;                      // 16384 waves
    const int rpw = (N + RECV_BLOCKS * 4 - 1) / (RECV_BLOCKS * 4);
    k_recv<<<RECV_BLOCKS, BLOCK, 0, stream>>>(xbf, eoutb, S, selfw, bias, out, N, rpw);
}

// Round 13
// 299.600 us; speedup vs baseline: 1.2675x; 1.2675x over previous
//
#include <hip/hip_runtime.h>

#define N_F     64
#define N_REL   32
#define BLOCK   256
#define SCAN_TILE 2048

typedef __attribute__((ext_vector_type(8))) short bf16x8;   // 8 bf16 = 4 VGPRs
typedef __attribute__((ext_vector_type(4))) float f32x4;

__device__ __forceinline__ unsigned short f2bf(float f) {
    unsigned u = __float_as_uint(f);
    u += 0x7FFF + ((u >> 16) & 1);          // RNE
    return (unsigned short)(u >> 16);
}

// ---------------------------------------------------------------------------
// K-pre: region-branched fusion of cast | relw | hist.
// Hist blocks persist their per-rel histogram to bh (plain stores only).
// ---------------------------------------------------------------------------
__global__ void __launch_bounds__(BLOCK) k_pre(const float* __restrict__ nf,
                                               const int* __restrict__ rel,
                                               const int* __restrict__ rcv,
                                               const float* __restrict__ basis,
                                               const float* __restrict__ coeff,
                                               unsigned short* __restrict__ xbf,
                                               unsigned short* __restrict__ Wsh,
                                               int* __restrict__ S,    // [0,N): cnt2, [N,..): bh
                                               int E, int total4, int N, int nbh,
                                               int nbCast, int nbRelw) {
    const int bid = blockIdx.x;
    if (bid < nbCast) {
        int i = bid * BLOCK + threadIdx.x;
        if (i < total4) {
            float4 v = ((const float4*)nf)[i];
            ushort4 o;
            o.x = f2bf(v.x); o.y = f2bf(v.y); o.z = f2bf(v.z); o.w = f2bf(v.w);
            ((ushort4*)xbf)[i] = o;
        }
    } else if (bid < nbCast + nbRelw) {
        int idx = (bid - nbCast) * BLOCK + threadIdx.x;
        if (idx < N_REL * N_F * N_F) {
            int r  = idx >> 12;
            int io = idx & 4095;          // k*64 + n
            int k  = io >> 6;
            int n  = io & 63;
            float acc = 0.f;
#pragma unroll
            for (int b = 0; b < 30; ++b)
                acc += coeff[r * 30 + b] * basis[b * (N_F * N_F) + io];
            int ks = k >> 5, kk = k & 31;
            int nt = n >> 4, nl = n & 15;
            int lane = ((kk >> 3) << 4) | nl;
            int j    = kk & 7;
            Wsh[((((r * 2 + ks) * 4 + nt) * 64 + lane) << 3) + j] = f2bf(acc);
        }
    } else {
        __shared__ int h[N_REL];
        if (threadIdx.x < N_REL) h[threadIdx.x] = 0;
        __syncthreads();
        const int bidh = bid - nbCast - nbRelw;
        int e = bidh * BLOCK + threadIdx.x;
        if (e < E) {
            atomicAdd(&h[rel[e]], 1);
            atomicAdd(&S[rcv[e]], 1);          // cnt2 (scattered, benign)
        }
        __syncthreads();
        if (threadIdx.x < N_REL)
            S[N + threadIdx.x * nbh + bidh] = h[threadIdx.x];   // bh (plain store)
    }
}

// ---------------------------------------------------------------------------
// Scan stage 1 over S = [cnt2 | bh] + region-branched cnt1 row-sums
// (blocks [npart, npart+32): block npart+r reduces bh row r -> cnt1[r]).
// ---------------------------------------------------------------------------
__global__ void k_scan_sums(const int* __restrict__ cur, int* __restrict__ part,
                            int* __restrict__ cnt1,
                            int nbins, int npart, int N, int nbh) {
    __shared__ int red[BLOCK];
    const int bid = blockIdx.x;
    if (bid >= npart) {
        const int r = bid - npart;
        const int* row = cur + N + (size_t)r * nbh;
        int s = 0;
        for (int i = threadIdx.x; i < nbh; i += BLOCK) s += row[i];
        red[threadIdx.x] = s;
        __syncthreads();
        for (int off = BLOCK / 2; off > 0; off >>= 1) {
            if (threadIdx.x < off) red[threadIdx.x] += red[threadIdx.x + off];
            __syncthreads();
        }
        if (threadIdx.x == 0) cnt1[r] = red[0];
        return;
    }
    int base = bid * SCAN_TILE;
    int s = 0;
    for (int i = threadIdx.x; i < SCAN_TILE; i += BLOCK) {
        int idx = base + i;
        s += (idx < nbins) ? cur[idx] : 0;
    }
    red[threadIdx.x] = s;
    __syncthreads();
    for (int off = BLOCK / 2; off > 0; off >>= 1) {
        if (threadIdx.x < off) red[threadIdx.x] += red[threadIdx.x + off];
        __syncthreads();
    }
    if (threadIdx.x == 0) part[bid] = red[0];
}

// ---------------------------------------------------------------------------
// Single-block middle: scan of tile sums + rel-bin bases (padded + unpadded)
// + pad-slot init incl. tail. cnt1 read directly (computed in k_scan_sums).
// ---------------------------------------------------------------------------
__global__ void k_scan_mid(const int* __restrict__ cnt1, int* __restrict__ base1,
                           int* __restrict__ ub1, int* __restrict__ part,
                           int* __restrict__ esrc, int* __restrict__ perm,
                           int npart, int Ppad) {
    __shared__ int buf[BLOCK];
    __shared__ int scnt[N_REL];
    __shared__ int sbase[N_REL + 1];
    __shared__ int stotal;
    const int tid = threadIdx.x;

    if (tid < N_REL) scnt[tid] = cnt1[tid];

    int v = (tid < npart) ? part[tid] : 0;
    buf[tid] = v;
    __syncthreads();
    for (int off = 1; off < BLOCK; off <<= 1) {
        int t = (tid >= off) ? buf[tid - off] : 0;
        __syncthreads();
        buf[tid] += t;
        __syncthreads();
    }
    if (tid < npart) part[tid] = buf[tid] - v;

    if (tid == 0) {
        int acc = 0, uacc = 0;
        for (int r = 0; r < N_REL; ++r) {
            base1[r] = acc;
            sbase[r] = acc;
            ub1[r]   = uacc;
            acc  += (scnt[r] + 15) & ~15;
            uacc += scnt[r];
        }
        base1[N_REL] = Ppad;
        sbase[N_REL] = Ppad;
        ub1[N_REL]   = uacc;
        stotal = acc;                  // actual padded total (<= Ppad)
    }
    __syncthreads();

    // intra-bin pad slots
    for (int i = tid; i < N_REL * 16; i += BLOCK) {
        int r = i >> 4, o = i & 15;
        int c  = scnt[r];
        int p0 = sbase[r] + c;
        int p1 = sbase[r] + ((c + 15) & ~15);
        int p  = p0 + o;
        if (p < p1) { perm[p] = -1; esrc[p] = 0; }
    }
    // tail [actual_total, Ppad)
    for (int p = stotal + tid; p < Ppad; p += BLOCK) {
        perm[p] = -1; esrc[p] = 0;
    }
}

// ---------------------------------------------------------------------------
// Scan stage 3 over S (+ fused tile->relation table)
// ---------------------------------------------------------------------------
__global__ void k_scan_apply_tile(int* __restrict__ cur, const int* __restrict__ part,
                                  const int* __restrict__ base1,
                                  unsigned char* __restrict__ trel,
                                  int nbins, int npart, int T) {
    if ((int)blockIdx.x >= npart) {
        int t = (blockIdx.x - npart) * BLOCK + threadIdx.x;
        if (t < T) {
            int p = t << 4;
            int r = 0;
#pragma unroll
            for (int i = 1; i < N_REL; ++i) r += (p >= base1[i]);
            trel[t] = (unsigned char)r;
        }
        return;
    }
    __shared__ int buf[BLOCK];
    int base_t = blockIdx.x * SCAN_TILE + threadIdx.x * 8;
    int loc[8];
    int s = 0;
#pragma unroll
    for (int j = 0; j < 8; ++j) {
        int idx = base_t + j;
        int v = (idx < nbins) ? cur[idx] : 0;
        loc[j] = s;
        s += v;
    }
    buf[threadIdx.x] = s;
    __syncthreads();
    for (int off = 1; off < BLOCK; off <<= 1) {
        int t = (threadIdx.x >= off) ? buf[threadIdx.x - off] : 0;
        __syncthreads();
        buf[threadIdx.x] += t;
        __syncthreads();
    }
    int excl = buf[threadIdx.x] - s + part[blockIdx.x];
#pragma unroll
    for (int j = 0; j < 8; ++j) {
        int idx = base_t + j;
        if (idx < nbins) cur[idx] = loc[j] + excl;
    }
}

// ---------------------------------------------------------------------------
// Scatter: pos1 via per-block scanned base + LDS rank (no global atomics);
// pos2 via mild scattered cur2 atomic. One barrier.
// ---------------------------------------------------------------------------
__global__ void __launch_bounds__(BLOCK) k_scatter1(const int* __restrict__ snd,
                                                    const int* __restrict__ rcv,
                                                    const int* __restrict__ rel,
                                                    int* S,
                                                    const int* __restrict__ base1,
                                                    const int* __restrict__ ub1,
                                                    int* __restrict__ esrc,
                                                    int* __restrict__ perm,
                                                    int E, int N, int nbh) {
    __shared__ int h[N_REL], bhb[N_REL];
    const int b = blockIdx.x;
    if (threadIdx.x < N_REL) {
        int g = S[N + threadIdx.x * nbh + b];              // includes +E offset
        bhb[threadIdx.x] = base1[threadIdx.x] + (g - E - ub1[threadIdx.x]);
        h[threadIdx.x] = 0;
    }
    __syncthreads();
    int e = b * BLOCK + threadIdx.x;
    if (e < E) {
        int r = rel[e];
        int rank = atomicAdd(&h[r], 1);
        int pos1 = bhb[r] + rank;
        int pos2 = atomicAdd(&S[rcv[e]], 1);
        esrc[pos1] = snd[e];
        perm[pos1] = pos2;
    }
}

// ---------------------------------------------------------------------------
// Phase A: per-tile GEMM -> bf16 edge rows at receiver-sorted positions.
// 1-deep prefetch of next tile's esrc/perm. No barriers/atomics.
// ---------------------------------------------------------------------------
__global__ void __launch_bounds__(BLOCK) k_gemm(const unsigned short* __restrict__ xbf,
                                                const int* __restrict__ esrc,
                                                const int* __restrict__ perm,
                                                const unsigned char* __restrict__ trel,
                                                const unsigned short* __restrict__ Wsh,
                                                unsigned short* __restrict__ eoutb,
                                                int T, int tpw, int dumprow) {
    __shared__ float ts[4][16 * 68];        // per-wave 16x64 transpose, stride 68
    const int tid  = threadIdx.x;
    const int lane = tid & 63;
    const int wave = tid >> 6;
    float* tb = ts[wave];

    const int gw = blockIdx.x * 4 + wave;
    const int t0 = gw * tpw;
    const int t1 = min(t0 + tpw, T);
    if (t0 >= T) return;

    const int row = lane & 15;
    const int kg  = lane >> 4;
    const int rr  = lane >> 2;      // store-phase row
    const int ch  = lane & 3;       // store-phase 16-col chunk

    int curR = -1;
    bf16x8 wf[2][4];

    int s_cur  = esrc[(t0 << 4) + row];
    int pm_cur = perm[(t0 << 4) + row];

    for (int t = t0; t < t1; ++t) {
        int s_nxt = 0, pm_nxt = -1;
        if (t + 1 < t1) {
            s_nxt  = esrc[((t + 1) << 4) + row];
            pm_nxt = perm[((t + 1) << 4) + row];
        }

        const int r = trel[t];
        if (r != curR) {
            curR = r;
#pragma unroll
            for (int ks = 0; ks < 2; ++ks)
#pragma unroll
                for (int nt = 0; nt < 4; ++nt)
                    wf[ks][nt] = *(const bf16x8*)(Wsh + ((((r * 2 + ks) * 4 + nt) * 64 + lane) << 3));
        }

        const size_t xb = ((size_t)s_cur << 6) + (kg << 3);
        bf16x8 a0 = *(const bf16x8*)(xbf + xb);
        bf16x8 a1 = *(const bf16x8*)(xbf + xb + 32);

        f32x4 acc[4];
#pragma unroll
        for (int nt = 0; nt < 4; ++nt) {
            acc[nt] = (f32x4){0.f, 0.f, 0.f, 0.f};
            acc[nt] = __builtin_amdgcn_mfma_f32_16x16x32_bf16(a0, wf[0][nt], acc[nt], 0, 0, 0);
            acc[nt] = __builtin_amdgcn_mfma_f32_16x16x32_bf16(a1, wf[1][nt], acc[nt], 0, 0, 0);
        }

        // C-layout (col=lane&15, row=kg*4+reg) -> LDS row-major
#pragma unroll
        for (int nt = 0; nt < 4; ++nt)
#pragma unroll
            for (int reg = 0; reg < 4; ++reg)
                tb[(kg * 4 + reg) * 68 + nt * 16 + (lane & 15)] = acc[nt][reg];

        asm volatile("s_waitcnt lgkmcnt(0)" ::: "memory");   // wave-local RAW

        int pmr = __shfl(pm_cur, rr);         // dest row of store-phase row
        pmr = (pmr < 0) ? dumprow : pmr;      // pad rows -> dump

        const float* src = tb + rr * 68 + ch * 16;
        unsigned pk[8];
#pragma unroll
        for (int q = 0; q < 4; ++q) {
            float4 v = *(const float4*)(src + q * 4);
            pk[2 * q]     = (unsigned)f2bf(v.x) | ((unsigned)f2bf(v.y) << 16);
            pk[2 * q + 1] = (unsigned)f2bf(v.z) | ((unsigned)f2bf(v.w) << 16);
        }
        unsigned short* dst = eoutb + (size_t)pmr * 64 + ch * 16;
        uint4 v0; v0.x = pk[0]; v0.y = pk[1]; v0.z = pk[2]; v0.w = pk[3];
        uint4 v1; v1.x = pk[4]; v1.y = pk[5]; v1.z = pk[6]; v1.w = pk[7];
        *(uint4*)dst       = v0;
        *(uint4*)(dst + 8) = v1;

        s_cur = s_nxt; pm_cur = pm_nxt;
    }
}

// ---------------------------------------------------------------------------
// Phase B: wave per node. 2-rows-per-load (g = lane>>5, c = lane&31), main
// loop unrolled to 8 rows/iter (4 independent dword loads in flight).
// Reduction = 1 shfl_xor + 2 shfls + select. Span boundaries prefetched.
// bf16 self-loop. No atomics/LDS.
// ---------------------------------------------------------------------------
__global__ void __launch_bounds__(BLOCK) k_recv(const unsigned short* __restrict__ xbf,
                                                const unsigned short* __restrict__ eoutb,
                                                const int* __restrict__ cur2,
                                                const float* __restrict__ selfw,
                                                const float* __restrict__ bias,
                                                float* __restrict__ out,
                                                int N, int rpw) {
    const int tid  = threadIdx.x;
    const int lane = tid & 63;
    const int wave = tid >> 6;
    const int gw   = blockIdx.x * 4 + wave;
    const int n0   = gw * rpw;
    const int n1   = min(n0 + rpw, N);
    if (n0 >= N) return;

    const int g = lane >> 5;        // row parity
    const int c = lane & 31;        // feat-pair index (feats 2c, 2c+1)

    float swcol[N_F];
#pragma unroll
    for (int i = 0; i < N_F; ++i) swcol[i] = selfw[i * N_F + lane];
    const float bv = bias[lane];

    // prefetch span boundaries: lane l holds cur2[n0-1+l]
    int bidx = n0 - 1 + lane;
    int bnd  = 0;
    if (bidx >= 0 && bidx < N && lane <= (n1 - n0)) bnd = cur2[bidx];

    for (int n = n0; n < n1; ++n) {
        const int li = n - n0;
        const int st = __shfl(bnd, li);
        const int en = __shfl(bnd, li + 1);

        float a0 = 0.f, a1 = 0.f;
        int j = st;
        for (; j + 8 <= en; j += 8) {
            unsigned u0 = *(const unsigned*)(eoutb + ((size_t)(j + g)     << 6) + (c << 1));
            unsigned u1 = *(const unsigned*)(eoutb + ((size_t)(j + 2 + g) << 6) + (c << 1));
            unsigned u2 = *(const unsigned*)(eoutb + ((size_t)(j + 4 + g) << 6) + (c << 1));
            unsigned u3 = *(const unsigned*)(eoutb + ((size_t)(j + 6 + g) << 6) + (c << 1));
            a0 += (__uint_as_float(u0 << 16) + __uint_as_float(u1 << 16)) +
                  (__uint_as_float(u2 << 16) + __uint_as_float(u3 << 16));
            a1 += (__uint_as_float(u0 & 0xFFFF0000u) + __uint_as_float(u1 & 0xFFFF0000u)) +
                  (__uint_as_float(u2 & 0xFFFF0000u) + __uint_as_float(u3 & 0xFFFF0000u));
        }
        if (j + 4 <= en) {
            unsigned u0 = *(const unsigned*)(eoutb + ((size_t)(j + g)     << 6) + (c << 1));
            unsigned u1 = *(const unsigned*)(eoutb + ((size_t)(j + 2 + g) << 6) + (c << 1));
            a0 += __uint_as_float(u0 << 16) + __uint_as_float(u1 << 16);
            a1 += __uint_as_float(u0 & 0xFFFF0000u) + __uint_as_float(u1 & 0xFFFF0000u);
            j += 4;
        }
        for (; j < en; j += 2) {
            int row = j + g;        // overread row <= en < Ppad: safe, masked
            unsigned u = *(const unsigned*)(eoutb + ((size_t)row << 6) + (c << 1));
            if (row < en) {
                a0 += __uint_as_float(u << 16);
                a1 += __uint_as_float(u & 0xFFFF0000u);
            }
        }
        a0 += __shfl_xor(a0, 32);
        a1 += __shfl_xor(a1, 32);
        float v0 = __shfl(a0, lane >> 1);
        float v1 = __shfl(a1, lane >> 1);
        float agg = (lane & 1) ? v1 : v0;

        // self-loop from bf16 x (broadcast uint4 = 8 feats)
        const uint4* xr = (const uint4*)(xbf + ((size_t)n << 6));
        float s0 = 0.f, s1 = 0.f, s2 = 0.f, s3 = 0.f;
#pragma unroll
        for (int q = 0; q < 8; ++q) {
            uint4 u = xr[q];
            float x0 = __uint_as_float(u.x << 16);
            float x1 = __uint_as_float(u.x & 0xFFFF0000u);
            float x2 = __uint_as_float(u.y << 16);
            float x3 = __uint_as_float(u.y & 0xFFFF0000u);
            float x4 = __uint_as_float(u.z << 16);
            float x5 = __uint_as_float(u.z & 0xFFFF0000u);
            float x6 = __uint_as_float(u.w << 16);
            float x7 = __uint_as_float(u.w & 0xFFFF0000u);
            s0 = __builtin_fmaf(x0, swcol[8 * q + 0], s0);
            s1 = __builtin_fmaf(x1, swcol[8 * q + 1], s1);
            s2 = __builtin_fmaf(x2, swcol[8 * q + 2], s2);
            s3 = __builtin_fmaf(x3, swcol[8 * q + 3], s3);
            s0 = __builtin_fmaf(x4, swcol[8 * q + 4], s0);
            s1 = __builtin_fmaf(x5, swcol[8 * q + 5], s1);
            s2 = __builtin_fmaf(x6, swcol[8 * q + 6], s2);
            s3 = __builtin_fmaf(x7, swcol[8 * q + 7], s3);
        }

        float dg  = (float)(en - st);
        float inv = 1.f / (dg < 1.f ? 1.f : dg);
        out[(size_t)n * N_F + lane] = agg * inv + (s0 + s1) + (s2 + s3) + bv;
    }
}

// ---------------------------------------------------------------------------
extern "C" void kernel_launch(void* const* d_in, const int* in_sizes, int n_in,
                              void* d_out, int out_size, void* d_ws, size_t ws_size,
                              hipStream_t stream) {
    const float* nf    = (const float*)d_in[0];
    const int*   snd   = (const int*)  d_in[1];
    const int*   rcv   = (const int*)  d_in[2];
    const int*   rel   = (const int*)  d_in[3];
    const float* basis = (const float*)d_in[4];
    const float* coeff = (const float*)d_in[5];
    const float* selfw = (const float*)d_in[6];
    const float* bias  = (const float*)d_in[7];
    float*       out   = (float*)d_out;

    const int N = in_sizes[0] / N_F;                  // 100000
    const int E = in_sizes[1];                        // 1000000
    const int Ppad = (E + N_REL * 15 + 15) & ~15;     // padded rel-sorted length
    const int T    = Ppad >> 4;                       // total 16-edge tiles
    const int total4 = N * N_F / 4;

    const int NB_CAST = (total4 + BLOCK - 1) / BLOCK;
    const int NB_RELW = (N_REL * N_F * N_F + BLOCK - 1) / BLOCK;
    const int NB_HIST = (E + BLOCK - 1) / BLOCK;      // == nbh
    const int nbh     = NB_HIST;

    const int SCAN_N = N + N_REL * nbh;               // combined scan length
    const int NPART  = (SCAN_N + SCAN_TILE - 1) / SCAN_TILE;   // <= 256

    // ws layout
    unsigned short* eoutb = (unsigned short*)d_ws;                    // Ppad*64 bf16
    unsigned short* Wsh   = eoutb + (size_t)Ppad * N_F;               // 131072
    unsigned short* xbf   = Wsh + (size_t)N_REL * N_F * N_F;          // N*64
    int* base1 = (int*)(xbf + (size_t)N * N_F);                       // 64
    int* ub1   = base1 + 64;                                          // 64
    int* cnt1  = ub1 + 64;                                            // 32
    int* part  = cnt1 + 32;                                           // 256
    int* S     = part + 256;                                          // SCAN_N (memset)
    int* esrc  = S + SCAN_N;                                          // Ppad
    int* perm  = esrc + Ppad;                                         // Ppad
    unsigned char* trel = (unsigned char*)(perm + Ppad);              // T

    hipMemsetAsync(S, 0, (size_t)SCAN_N * sizeof(int), stream);

    k_pre<<<NB_CAST + NB_RELW + NB_HIST, BLOCK, 0, stream>>>(
        nf, rel, rcv, basis, coeff, xbf, Wsh, S, E, total4, N, nbh, NB_CAST, NB_RELW);

    k_scan_sums<<<NPART + N_REL, BLOCK, 0, stream>>>(S, part, cnt1, SCAN_N, NPART, N, nbh);
    k_scan_mid <<<1, BLOCK, 0, stream>>>(cnt1, base1, ub1, part, esrc, perm, NPART, Ppad);

    const int NB_TREL = (T + BLOCK - 1) / BLOCK;
    k_scan_apply_tile<<<NPART + NB_TREL, BLOCK, 0, stream>>>(S, part, base1, trel,
                                                             SCAN_N, NPART, T);

    k_scatter1<<<nbh, BLOCK, 0, stream>>>(snd, rcv, rel, S, base1, ub1, esrc, perm,
                                          E, N, nbh);

    const int GEMM_BLOCKS = 2048;                      // 8192 waves
    const int tpw = (T + GEMM_BLOCKS * 4 - 1) / (GEMM_BLOCKS * 4);
    k_gemm<<<GEMM_BLOCKS, BLOCK, 0, stream>>>(xbf, esrc, perm, trel, Wsh, eoutb, T, tpw, E);

    const int RECV_BLOCKS = 4096;                      // 16384 waves
    const int rpw = (N + RECV_BLOCKS * 4 - 1) / (RECV_BLOCKS * 4);
    k_recv<<<RECV_BLOCKS, BLOCK, 0, stream>>>(xbf, eoutb, S, selfw, bias, out, N, rpw);
}